// Round 1
// baseline (708.832 us; speedup 1.0000x reference)
//
#include <hip/hip_runtime.h>
#include <math.h>

#define N_NODES 100000
#define N_EDGES 640000
#define C 128
#define E_TOT (N_EDGES + N_NODES)
#define BN 64

// ---------------- dst-bucket linked list (shared by both layers) -------------
__global__ void link_kernel(const int* __restrict__ ei, int* __restrict__ head,
                            int* __restrict__ nxt) {
    int i = blockIdx.x * blockDim.x + threadIdx.x;
    if (i >= E_TOT) return;
    int d = (i < N_EDGES) ? ei[N_EDGES + i] : (i - N_EDGES);
    int old = atomicExch(&head[d], i);
    nxt[i] = old;
}

// ---------------- fused 3-way GEMM: xl = xW_l^T+b_l, xr = xW_r^T+b_r,
//                  res = xW_res^T + bias ------------------------------------
__global__ void gemm3_kernel(const float* __restrict__ x,
                             const float* __restrict__ Wl, const float* __restrict__ bl,
                             const float* __restrict__ Wr, const float* __restrict__ br,
                             const float* __restrict__ Wres, const float* __restrict__ bres,
                             float* __restrict__ xl, float* __restrict__ xr,
                             float* __restrict__ res) {
    __shared__ __align__(16) float xs[BN][C];      // 32 KB, read as broadcast
    __shared__ __align__(16) float wt[32][132];    // 16.9 KB, transposed W chunk

    const int tid = threadIdx.x;
    const int n0 = blockIdx.x * BN;

    // stage x tile (coalesced float4)
    for (int li = tid; li < BN * (C / 4); li += 256) {
        int n  = li >> 5;            // 32 float4 per row
        int c4 = (li & 31) * 4;
        float4 v = make_float4(0.f, 0.f, 0.f, 0.f);
        if (n0 + n < N_NODES)
            v = *(const float4*)(x + (size_t)(n0 + n) * C + c4);
        *(float4*)&xs[n][c4] = v;
    }

    const float* Ws[3] = {Wl, Wr, Wres};
    const float* Bs[3] = {bl, br, bres};
    float*       Os[3] = {xl, xr, res};

    const int jq = tid & 31;      // 32 col-groups of 4
    const int g  = tid >> 5;      // 8 node-groups of 8
    const int j0 = jq * 4;
    const int nb = g * 8;

    for (int wsel = 0; wsel < 3; ++wsel) {
        const float* W = Ws[wsel];
        float acc[8][4];
        #pragma unroll
        for (int a = 0; a < 8; ++a)
            #pragma unroll
            for (int b = 0; b < 4; ++b) acc[a][b] = 0.f;

        for (int kc = 0; kc < 4; ++kc) {
            __syncthreads();
            // stage transposed chunk: wt[kk][j] = W[j*C + kc*32 + kk]
            for (int li = tid; li < 1024; li += 256) {
                int j  = li >> 3;            // 8 float4 per row of 32 k's
                int t8 = li & 7;
                float4 w4 = *(const float4*)(W + (size_t)j * C + kc * 32 + t8 * 4);
                wt[t8 * 4 + 0][j] = w4.x;
                wt[t8 * 4 + 1][j] = w4.y;
                wt[t8 * 4 + 2][j] = w4.z;
                wt[t8 * 4 + 3][j] = w4.w;
            }
            __syncthreads();

            #pragma unroll 4
            for (int kk = 0; kk < 32; ++kk) {
                const int k = kc * 32 + kk;
                float4 w4 = *(const float4*)&wt[kk][j0];
                float xv[8];
                #pragma unroll
                for (int nn = 0; nn < 8; ++nn) xv[nn] = xs[nb + nn][k];
                #pragma unroll
                for (int nn = 0; nn < 8; ++nn) {
                    acc[nn][0] += w4.x * xv[nn];
                    acc[nn][1] += w4.y * xv[nn];
                    acc[nn][2] += w4.z * xv[nn];
                    acc[nn][3] += w4.w * xv[nn];
                }
            }
        }

        float4 b4 = *(const float4*)(Bs[wsel] + j0);
        #pragma unroll
        for (int nn = 0; nn < 8; ++nn) {
            int n = n0 + nb + nn;
            if (n < N_NODES) {
                float4 o;
                o.x = acc[nn][0] + b4.x;
                o.y = acc[nn][1] + b4.y;
                o.z = acc[nn][2] + b4.z;
                o.w = acc[nn][3] + b4.w;
                *(float4*)(Os[wsel] + (size_t)n * C + j0) = o;
            }
        }
    }
}

// ---------------- per-node online-softmax attention + aggregate --------------
// one wave per dst node; lane owns channels (lane, lane+64)
template <int RELU>
__global__ void node_kernel(const float* __restrict__ xl, const float* __restrict__ xr,
                            const float* __restrict__ att, const int* __restrict__ head,
                            const int* __restrict__ nxt, const int* __restrict__ ei,
                            const float* __restrict__ resin, float* __restrict__ outp) {
    const int d = blockIdx.x * 4 + (threadIdx.x >> 6);
    const int lane = threadIdx.x & 63;
    if (d >= N_NODES) return;

    const float xr0 = xr[(size_t)d * C + lane];
    const float xr1 = xr[(size_t)d * C + 64 + lane];
    const float a0 = att[lane];
    const float a1 = att[64 + lane];

    float M = -INFINITY, S = 0.f, O0 = 0.f, O1 = 0.f;

    int idx = head[d];
    while (idx >= 0) {
        const int s  = (idx < N_EDGES) ? ei[idx] : (idx - N_EDGES);
        const int nx = nxt[idx];
        const float* row = xl + (size_t)s * C;
        const float x0 = row[lane];
        const float x1 = row[64 + lane];

        float m0 = x0 + xr0; m0 = (m0 > 0.f) ? m0 : 0.2f * m0;
        float m1 = x1 + xr1; m1 = (m1 > 0.f) ? m1 : 0.2f * m1;
        float p = a0 * m0 + a1 * m1;
        #pragma unroll
        for (int off = 32; off; off >>= 1) p += __shfl_xor(p, off, 64);

        const float nM = fmaxf(M, p);
        const float sc = __expf(M - nM);   // 0 on first edge (M = -inf)
        const float w  = __expf(p - nM);
        S  = S * sc + w;
        O0 = O0 * sc + w * x0;
        O1 = O1 * sc + w * x1;
        M  = nM;
        idx = nx;
    }

    const float inv = 1.f / S;
    float r0 = resin[(size_t)d * C + lane] + O0 * inv;
    float r1 = resin[(size_t)d * C + 64 + lane] + O1 * inv;
    if (RELU) { r0 = fmaxf(r0, 0.f); r1 = fmaxf(r1, 0.f); }
    outp[(size_t)d * C + lane] = r0;
    outp[(size_t)d * C + 64 + lane] = r1;
}

// ---------------------------------------------------------------------------
extern "C" void kernel_launch(void* const* d_in, const int* in_sizes, int n_in,
                              void* d_out, int out_size, void* d_ws, size_t ws_size,
                              hipStream_t stream) {
    const int*   ei  = (const int*)d_in[0];
    const float* emb = (const float*)d_in[1];
    // per-layer params: 0 Wl, 1 bl, 2 Wr, 3 br, 4 att, 5 Wres, 6 bias
    const float* L1[7];
    const float* L2[7];
    for (int i = 0; i < 7; ++i) L1[i] = (const float*)d_in[2 + i];
    for (int i = 0; i < 7; ++i) L2[i] = (const float*)d_in[9 + i];
    float* out = (float*)d_out;

    float* xl   = (float*)d_ws;
    float* xr   = xl + (size_t)N_NODES * C;
    float* h    = xr + (size_t)N_NODES * C;
    int*   head = (int*)(h + (size_t)N_NODES * C);
    int*   nxt  = head + N_NODES;

    hipMemsetAsync(head, 0xFF, N_NODES * sizeof(int), stream);  // head = -1
    link_kernel<<<(E_TOT + 255) / 256, 256, 0, stream>>>(ei, head, nxt);

    const int gblocks = (N_NODES + BN - 1) / BN;

    // ---- layer 1 ----
    gemm3_kernel<<<gblocks, 256, 0, stream>>>(emb, L1[0], L1[1], L1[2], L1[3],
                                              L1[5], L1[6], xl, xr, h);
    node_kernel<1><<<N_NODES / 4, 256, 0, stream>>>(xl, xr, L1[4], head, nxt, ei, h, h);

    // ---- layer 2 ----
    gemm3_kernel<<<gblocks, 256, 0, stream>>>(h, L2[0], L2[1], L2[2], L2[3],
                                              L2[5], L2[6], xl, xr, out);
    node_kernel<0><<<N_NODES / 4, 256, 0, stream>>>(xl, xr, L2[4], head, nxt, ei, out, out);
}

// Round 2
// 463.666 us; speedup vs baseline: 1.5288x; 1.5288x over previous
//
#include <hip/hip_runtime.h>
#include <math.h>

#define N_NODES 100000
#define N_EDGES 640000
#define C 128
#define E_TOT (N_EDGES + N_NODES)

typedef __attribute__((ext_vector_type(8))) short short8;
typedef __attribute__((ext_vector_type(4))) float floatx4;
typedef unsigned int uint;
typedef unsigned short ushort;

__device__ __forceinline__ ushort f2bf(float f) {
    union { float f; uint u; } v; v.f = f;
    uint r = v.u + 0x7fffu + ((v.u >> 16) & 1u);   // RNE
    return (ushort)(r >> 16);
}
__device__ __forceinline__ float bf2f(ushort b) {
    union { uint u; float f; } v; v.u = ((uint)b) << 16; return v.f;
}

// ---------------- dst-bucket linked list (shared by both layers) -------------
__global__ void link_kernel(const int* __restrict__ ei, int* __restrict__ head,
                            int* __restrict__ nxt) {
    int i = blockIdx.x * blockDim.x + threadIdx.x;
    if (i >= E_TOT) return;
    int d = (i < N_EDGES) ? ei[N_EDGES + i] : (i - N_EDGES);
    int old = atomicExch(&head[d], i);
    nxt[i] = old;
}

// ---------------- convert 6 weight matrices fp32 -> bf16 --------------------
__global__ void conv_w(const float* __restrict__ w0, const float* __restrict__ w1,
                       const float* __restrict__ w2, const float* __restrict__ w3,
                       const float* __restrict__ w4, const float* __restrict__ w5,
                       ushort* __restrict__ out) {
    int t = blockIdx.x * 256 + threadIdx.x;      // 12288 threads, 8 elems each
    int m = t >> 11;
    int off = (t & 2047) * 8;
    const float* src = (m == 0) ? w0 : (m == 1) ? w1 : (m == 2) ? w2
                      : (m == 3) ? w3 : (m == 4) ? w4 : w5;
    float4 v0 = *(const float4*)(src + off);
    float4 v1 = *(const float4*)(src + off + 4);
    ushort tmp[8];
    tmp[0] = f2bf(v0.x); tmp[1] = f2bf(v0.y); tmp[2] = f2bf(v0.z); tmp[3] = f2bf(v0.w);
    tmp[4] = f2bf(v1.x); tmp[5] = f2bf(v1.y); tmp[6] = f2bf(v1.z); tmp[7] = f2bf(v1.w);
    *(uint4*)(out + (size_t)m * 16384 + off) = *(uint4*)tmp;
}

// ---------------- fused 3-way GEMM via bf16 MFMA ----------------------------
// out[n][j] = sum_k x[n][k] * W[j][k] + b[j]   for W in {Wl, Wr, Wres}
// block: 512 thr = 8 waves; 64-node tile; wave w owns cols [16w,16w+16)
template <int IN_F32>
__global__ __launch_bounds__(512, 1)
void gemm3_mfma(const void* __restrict__ xin,
                const ushort* __restrict__ wb,    // [3][128][128] bf16
                const float* __restrict__ bl, const float* __restrict__ br,
                const float* __restrict__ bres,
                ushort* __restrict__ xl, ushort* __restrict__ xr,
                ushort* __restrict__ res) {
    __shared__ ushort xs[64][136];                // +8 pad: 2-way banks only
    const int tid = threadIdx.x;
    const int wave = tid >> 6, lane = tid & 63;
    const int quad = lane >> 4, l16 = lane & 15;
    const int n0 = blockIdx.x * 64;

    // B fragments in registers: B[k][n] = W[col n][k], contiguous 16B per lane
    short8 bfr[3][4];
    const int col = wave * 16 + l16;
    #pragma unroll
    for (int ws = 0; ws < 3; ++ws)
        #pragma unroll
        for (int ks = 0; ks < 4; ++ks)
            bfr[ws][ks] = *(const short8*)(wb + (size_t)ws * 16384 + col * 128 + ks * 32 + quad * 8);

    // stage x tile -> bf16 LDS
    {
        const int node = tid >> 3;
        const int kc = (tid & 7) * 16;
        const int n = n0 + node;
        ushort tmp[16];
        if (n < N_NODES) {
            if (IN_F32) {
                const float* src = (const float*)xin + (size_t)n * C + kc;
                float4 v[4];
                #pragma unroll
                for (int i = 0; i < 4; ++i) v[i] = ((const float4*)src)[i];
                #pragma unroll
                for (int i = 0; i < 4; ++i) {
                    tmp[i * 4 + 0] = f2bf(v[i].x); tmp[i * 4 + 1] = f2bf(v[i].y);
                    tmp[i * 4 + 2] = f2bf(v[i].z); tmp[i * 4 + 3] = f2bf(v[i].w);
                }
            } else {
                const ushort* src = (const ushort*)xin + (size_t)n * C + kc;
                *(uint4*)&tmp[0] = *(const uint4*)src;
                *(uint4*)&tmp[8] = *(const uint4*)(src + 8);
            }
        } else {
            #pragma unroll
            for (int i = 0; i < 16; ++i) tmp[i] = 0;
        }
        *(uint4*)&xs[node][kc]     = *(uint4*)&tmp[0];
        *(uint4*)&xs[node][kc + 8] = *(uint4*)&tmp[8];
    }
    __syncthreads();

    floatx4 acc[4][3];
    #pragma unroll
    for (int rt = 0; rt < 4; ++rt)
        #pragma unroll
        for (int ws = 0; ws < 3; ++ws)
            acc[rt][ws] = (floatx4){0.f, 0.f, 0.f, 0.f};

    #pragma unroll
    for (int rt = 0; rt < 4; ++rt) {
        short8 a[4];
        #pragma unroll
        for (int ks = 0; ks < 4; ++ks)
            a[ks] = *(const short8*)&xs[rt * 16 + l16][ks * 32 + quad * 8];
        #pragma unroll
        for (int ws = 0; ws < 3; ++ws)
            #pragma unroll
            for (int ks = 0; ks < 4; ++ks)
                acc[rt][ws] = __builtin_amdgcn_mfma_f32_16x16x32_bf16(a[ks], bfr[ws][ks], acc[rt][ws], 0, 0, 0);
    }

    // epilogue: C/D layout col=lane&15, row=quad*4+reg
    float bias[3] = { bl[col], br[col], bres[col] };
    ushort* Os[3] = { xl, xr, res };
    #pragma unroll
    for (int ws = 0; ws < 3; ++ws)
        #pragma unroll
        for (int rt = 0; rt < 4; ++rt)
            #pragma unroll
            for (int r = 0; r < 4; ++r) {
                int row = n0 + rt * 16 + quad * 4 + r;
                if (row < N_NODES)
                    Os[ws][(size_t)row * C + col] = f2bf(acc[rt][ws][r] + bias[ws]);
            }
}

// ---------------- per-node online-softmax attention + aggregate --------------
// one wave per dst; lane owns channel pair (2*lane, 2*lane+1)
template <int OUT_BF16, int RELU>
__global__ void node_kernel(const ushort* __restrict__ xl, const ushort* __restrict__ xr,
                            const float* __restrict__ att, const int* __restrict__ head,
                            const int* __restrict__ nxt, const int* __restrict__ ei,
                            const ushort* __restrict__ resin, void* __restrict__ outp) {
    const int d = blockIdx.x * 4 + (threadIdx.x >> 6);
    const int lane = threadIdx.x & 63;

    const uint uxr = *(const uint*)(xr + (size_t)d * C + 2 * lane);
    const float xr0 = bf2f((ushort)(uxr & 0xffffu));
    const float xr1 = bf2f((ushort)(uxr >> 16));
    const float2 a = *(const float2*)(att + 2 * lane);

    float M = -INFINITY, S = 0.f, O0 = 0.f, O1 = 0.f;

    int idx = head[d];
    while (idx >= 0) {
        const int s  = (idx < N_EDGES) ? ei[idx] : (idx - N_EDGES);
        const int nx = nxt[idx];
        const uint ux = *(const uint*)(xl + (size_t)s * C + 2 * lane);
        const float x0 = bf2f((ushort)(ux & 0xffffu));
        const float x1 = bf2f((ushort)(ux >> 16));

        float m0 = x0 + xr0; m0 = (m0 > 0.f) ? m0 : 0.2f * m0;
        float m1 = x1 + xr1; m1 = (m1 > 0.f) ? m1 : 0.2f * m1;
        float p = a.x * m0 + a.y * m1;
        #pragma unroll
        for (int off = 32; off; off >>= 1) p += __shfl_xor(p, off, 64);

        const float nM = fmaxf(M, p);
        const float sc = __expf(M - nM);
        const float w  = __expf(p - nM);
        S  = S * sc + w;
        O0 = O0 * sc + w * x0;
        O1 = O1 * sc + w * x1;
        M  = nM;
        idx = nx;
    }

    const float inv = 1.f / S;
    const uint urs = *(const uint*)(resin + (size_t)d * C + 2 * lane);
    float r0 = bf2f((ushort)(urs & 0xffffu)) + O0 * inv;
    float r1 = bf2f((ushort)(urs >> 16))     + O1 * inv;
    if (RELU) { r0 = fmaxf(r0, 0.f); r1 = fmaxf(r1, 0.f); }
    if (OUT_BF16) {
        uint packed = (uint)f2bf(r0) | ((uint)f2bf(r1) << 16);
        *((uint*)outp + (size_t)d * (C / 2) + lane) = packed;
    } else {
        float2 o; o.x = r0; o.y = r1;
        *((float2*)outp + (size_t)d * (C / 2) + lane) = o;
    }
}

// ---------------------------------------------------------------------------
extern "C" void kernel_launch(void* const* d_in, const int* in_sizes, int n_in,
                              void* d_out, int out_size, void* d_ws, size_t ws_size,
                              hipStream_t stream) {
    const int*   ei  = (const int*)d_in[0];
    const float* emb = (const float*)d_in[1];
    const float* L1[7];
    const float* L2[7];
    for (int i = 0; i < 7; ++i) L1[i] = (const float*)d_in[2 + i];
    for (int i = 0; i < 7; ++i) L2[i] = (const float*)d_in[9 + i];
    float* out = (float*)d_out;

    const size_t NC = (size_t)N_NODES * C;
    ushort* xl  = (ushort*)d_ws;
    ushort* xr  = xl + NC;
    ushort* h   = xr + NC;     // layer1 res -> node1 in-place -> h (gemm2 input)
    ushort* r2  = h + NC;      // layer2 res
    ushort* wb  = r2 + NC;     // 6*16384 bf16 weights
    int* head   = (int*)(wb + 6 * 16384);
    int* nxt    = head + N_NODES;

    hipMemsetAsync(head, 0xFF, N_NODES * sizeof(int), stream);
    link_kernel<<<(E_TOT + 255) / 256, 256, 0, stream>>>(ei, head, nxt);
    conv_w<<<48, 256, 0, stream>>>(L1[0], L1[2], L1[5], L2[0], L2[2], L2[5], wb);

    const int gblocks = (N_NODES + 63) / 64;

    // ---- layer 1 ----
    gemm3_mfma<1><<<gblocks, 512, 0, stream>>>(emb, wb, L1[1], L1[3], L1[6], xl, xr, h);
    node_kernel<1, 1><<<N_NODES / 4, 256, 0, stream>>>(xl, xr, L1[4], head, nxt, ei, h, h);

    // ---- layer 2 ----
    gemm3_mfma<0><<<gblocks, 512, 0, stream>>>(h, wb + 3 * 16384, L2[1], L2[3], L2[6], xl, xr, r2);
    node_kernel<0, 0><<<N_NODES / 4, 256, 0, stream>>>(xl, xr, L2[4], head, nxt, ei, r2, out);
}

// Round 3
// 376.072 us; speedup vs baseline: 1.8848x; 1.2329x over previous
//
#include <hip/hip_runtime.h>
#include <math.h>

#define N_NODES 100000
#define N_EDGES 640000
#define C 128
#define E_TOT (N_EDGES + N_NODES)
#define NB_SCAN ((N_NODES + 255) / 256)   // 391

typedef __attribute__((ext_vector_type(8))) short short8;
typedef __attribute__((ext_vector_type(4))) float floatx4;
typedef unsigned int uint;
typedef unsigned short ushort;

__device__ __forceinline__ ushort f2bf(float f) {
    union { float f; uint u; } v; v.f = f;
    uint r = v.u + 0x7fffu + ((v.u >> 16) & 1u);   // RNE
    return (ushort)(r >> 16);
}
__device__ __forceinline__ float bf2f(ushort b) {
    union { uint u; float f; } v; v.u = ((uint)b) << 16; return v.f;
}
__device__ __forceinline__ float bflo(uint u) {
    union { uint u; float f; } v; v.u = u << 16; return v.f;
}
__device__ __forceinline__ float bfhi(uint u) {
    union { uint u; float f; } v; v.u = u & 0xffff0000u; return v.f;
}

// ======================= CSR build =========================================
__global__ void hist_kernel(const int* __restrict__ ei, int* __restrict__ cnt) {
    int i = blockIdx.x * 256 + threadIdx.x;
    if (i >= E_TOT) return;
    int d = (i < N_EDGES) ? ei[N_EDGES + i] : (i - N_EDGES);
    atomicAdd(&cnt[d], 1);
}

__global__ void scan_block(const int* __restrict__ cnt, int* __restrict__ row_off,
                           int* __restrict__ bsum) {
    __shared__ int s[256];
    int t = threadIdx.x, idx = blockIdx.x * 256 + t;
    int v = (idx < N_NODES) ? cnt[idx] : 0;
    s[t] = v;
    __syncthreads();
    #pragma unroll
    for (int off = 1; off < 256; off <<= 1) {
        int x = (t >= off) ? s[t - off] : 0;
        __syncthreads();
        s[t] += x;
        __syncthreads();
    }
    if (idx < N_NODES) row_off[idx] = s[t] - v;      // exclusive
    if (t == 255) bsum[blockIdx.x] = s[255];
}

__global__ void scan_tops(int* __restrict__ bsum) {
    __shared__ int s[512];
    int t = threadIdx.x;
    int v = (t < NB_SCAN) ? bsum[t] : 0;
    s[t] = v;
    __syncthreads();
    #pragma unroll
    for (int off = 1; off < 512; off <<= 1) {
        int x = (t >= off) ? s[t - off] : 0;
        __syncthreads();
        s[t] += x;
        __syncthreads();
    }
    if (t < NB_SCAN) bsum[t] = s[t] - v;             // exclusive
}

__global__ void add_off(int* __restrict__ row_off, const int* __restrict__ bsum,
                        int* __restrict__ cursor) {
    int idx = blockIdx.x * 256 + threadIdx.x;
    if (idx < N_NODES) {
        int r = row_off[idx] + bsum[idx >> 8];
        row_off[idx] = r;
        cursor[idx] = r;
    }
    if (idx == 0) row_off[N_NODES] = E_TOT;
}

__global__ void scatter_kernel(const int* __restrict__ ei, int* __restrict__ cursor,
                               int* __restrict__ colsrc) {
    int i = blockIdx.x * 256 + threadIdx.x;
    if (i >= E_TOT) return;
    int d, s;
    if (i < N_EDGES) { d = ei[N_EDGES + i]; s = ei[i]; }
    else             { d = i - N_EDGES;     s = i - N_EDGES; }
    int pos = atomicAdd(&cursor[d], 1);
    colsrc[pos] = s;
}

// ======================= weight convert ====================================
__global__ void conv_w(const float* __restrict__ w0, const float* __restrict__ w1,
                       const float* __restrict__ w2, const float* __restrict__ w3,
                       const float* __restrict__ w4, const float* __restrict__ w5,
                       ushort* __restrict__ out) {
    int t = blockIdx.x * 256 + threadIdx.x;
    int m = t >> 11;
    int off = (t & 2047) * 8;
    const float* src = (m == 0) ? w0 : (m == 1) ? w1 : (m == 2) ? w2
                      : (m == 3) ? w3 : (m == 4) ? w4 : w5;
    float4 v0 = *(const float4*)(src + off);
    float4 v1 = *(const float4*)(src + off + 4);
    ushort tmp[8];
    tmp[0] = f2bf(v0.x); tmp[1] = f2bf(v0.y); tmp[2] = f2bf(v0.z); tmp[3] = f2bf(v0.w);
    tmp[4] = f2bf(v1.x); tmp[5] = f2bf(v1.y); tmp[6] = f2bf(v1.z); tmp[7] = f2bf(v1.w);
    *(uint4*)(out + (size_t)m * 16384 + off) = *(uint4*)tmp;
}

// ======================= fused 3-way GEMM (bf16 MFMA) ======================
template <int IN_F32>
__global__ __launch_bounds__(512)
void gemm3_mfma(const void* __restrict__ xin,
                const ushort* __restrict__ wb,
                const float* __restrict__ bl, const float* __restrict__ br,
                const float* __restrict__ bres,
                ushort* __restrict__ xl, ushort* __restrict__ xr,
                ushort* __restrict__ res) {
    __shared__ ushort xs[64][136];
    const int tid = threadIdx.x;
    const int wave = tid >> 6, lane = tid & 63;
    const int quad = lane >> 4, l16 = lane & 15;
    const int n0 = blockIdx.x * 64;

    short8 bfr[3][4];
    const int col = wave * 16 + l16;
    #pragma unroll
    for (int ws = 0; ws < 3; ++ws)
        #pragma unroll
        for (int ks = 0; ks < 4; ++ks)
            bfr[ws][ks] = *(const short8*)(wb + (size_t)ws * 16384 + col * 128 + ks * 32 + quad * 8);

    {
        const int node = tid >> 3;
        const int kc = (tid & 7) * 16;
        const int n = n0 + node;
        ushort tmp[16];
        if (n < N_NODES) {
            if (IN_F32) {
                const float* src = (const float*)xin + (size_t)n * C + kc;
                float4 v[4];
                #pragma unroll
                for (int i = 0; i < 4; ++i) v[i] = ((const float4*)src)[i];
                #pragma unroll
                for (int i = 0; i < 4; ++i) {
                    tmp[i * 4 + 0] = f2bf(v[i].x); tmp[i * 4 + 1] = f2bf(v[i].y);
                    tmp[i * 4 + 2] = f2bf(v[i].z); tmp[i * 4 + 3] = f2bf(v[i].w);
                }
            } else {
                const ushort* src = (const ushort*)xin + (size_t)n * C + kc;
                *(uint4*)&tmp[0] = *(const uint4*)src;
                *(uint4*)&tmp[8] = *(const uint4*)(src + 8);
            }
        } else {
            #pragma unroll
            for (int i = 0; i < 16; ++i) tmp[i] = 0;
        }
        *(uint4*)&xs[node][kc]     = *(uint4*)&tmp[0];
        *(uint4*)&xs[node][kc + 8] = *(uint4*)&tmp[8];
    }
    __syncthreads();

    floatx4 acc[4][3];
    #pragma unroll
    for (int rt = 0; rt < 4; ++rt)
        #pragma unroll
        for (int ws = 0; ws < 3; ++ws)
            acc[rt][ws] = (floatx4){0.f, 0.f, 0.f, 0.f};

    #pragma unroll
    for (int rt = 0; rt < 4; ++rt) {
        short8 a[4];
        #pragma unroll
        for (int ks = 0; ks < 4; ++ks)
            a[ks] = *(const short8*)&xs[rt * 16 + l16][ks * 32 + quad * 8];
        #pragma unroll
        for (int ws = 0; ws < 3; ++ws)
            #pragma unroll
            for (int ks = 0; ks < 4; ++ks)
                acc[rt][ws] = __builtin_amdgcn_mfma_f32_16x16x32_bf16(a[ks], bfr[ws][ks], acc[rt][ws], 0, 0, 0);
    }

    float bias[3] = { bl[col], br[col], bres[col] };
    ushort* Os[3] = { xl, xr, res };
    #pragma unroll
    for (int ws = 0; ws < 3; ++ws)
        #pragma unroll
        for (int rt = 0; rt < 4; ++rt)
            #pragma unroll
            for (int r = 0; r < 4; ++r) {
                int row = n0 + rt * 16 + quad * 4 + r;
                if (row < N_NODES)
                    Os[ws][(size_t)row * C + col] = f2bf(acc[rt][ws][r] + bias[ws]);
            }
}

// ======================= node kernel: CSR, 4 edges/wave ====================
// wave per dst; slot = lane>>4 (edge within batch of 4), g = lane&15 (8 ch)
template <int OUT_BF16, int RELU>
__global__ __launch_bounds__(256)
void node_kernel(const ushort* __restrict__ xl, const ushort* __restrict__ xr,
                 const float* __restrict__ att, const int* __restrict__ row_off,
                 const int* __restrict__ colsrc,
                 const ushort* __restrict__ resin, void* __restrict__ outp) {
    const int d = blockIdx.x * 4 + (threadIdx.x >> 6);
    const int lane = threadIdx.x & 63;
    const int slot = lane >> 4;
    const int g = lane & 15;
    const int base_c = g * 8;

    // xr chunk (8 channels, bf16 -> f32)
    uint4 uxr = *(const uint4*)(xr + (size_t)d * C + base_c);
    float xrv[8];
    xrv[0] = bflo(uxr.x); xrv[1] = bfhi(uxr.x);
    xrv[2] = bflo(uxr.y); xrv[3] = bfhi(uxr.y);
    xrv[4] = bflo(uxr.z); xrv[5] = bfhi(uxr.z);
    xrv[6] = bflo(uxr.w); xrv[7] = bfhi(uxr.w);

    float4 a0 = *(const float4*)(att + base_c);
    float4 a1 = *(const float4*)(att + base_c + 4);
    float av[8] = { a0.x, a0.y, a0.z, a0.w, a1.x, a1.y, a1.z, a1.w };

    const int start = row_off[d];
    const int end   = row_off[d + 1];

    float S = 0.f;
    float O[8];
    #pragma unroll
    for (int c = 0; c < 8; ++c) O[c] = 0.f;

    // prefetch first batch
    int eidx = start + slot;
    bool v = eidx < end;
    int src = v ? colsrc[eidx] : 0;
    uint4 raw = make_uint4(0, 0, 0, 0);
    if (v) raw = *(const uint4*)(xl + (size_t)src * C + base_c);

    for (int base = start; base < end; base += 4) {
        const bool  cv   = v;
        const uint4 craw = raw;

        // prefetch next batch
        eidx = base + 4 + slot;
        v = eidx < end;
        src = v ? colsrc[eidx] : 0;
        raw = make_uint4(0, 0, 0, 0);
        if (v) raw = *(const uint4*)(xl + (size_t)src * C + base_c);

        float xv[8];
        xv[0] = bflo(craw.x); xv[1] = bfhi(craw.x);
        xv[2] = bflo(craw.y); xv[3] = bfhi(craw.y);
        xv[4] = bflo(craw.z); xv[5] = bfhi(craw.z);
        xv[6] = bflo(craw.w); xv[7] = bfhi(craw.w);

        float p = 0.f;
        #pragma unroll
        for (int c = 0; c < 8; ++c) {
            float m = xv[c] + xrv[c];
            m = fmaxf(m, 0.2f * m);          // leaky relu, slope 0.2 < 1
            p = fmaf(av[c], m, p);
        }
        // reduce over the 16 lanes of this slot
        #pragma unroll
        for (int off = 1; off < 16; off <<= 1) p += __shfl_xor(p, off, 64);

        const float w = cv ? __expf(p) : 0.f;
        S += w;
        #pragma unroll
        for (int c = 0; c < 8; ++c) O[c] = fmaf(w, xv[c], O[c]);
    }

    // combine the 4 slots (lanes xor 16, 32)
    #pragma unroll
    for (int off = 16; off < 64; off <<= 1) {
        S += __shfl_xor(S, off, 64);
        #pragma unroll
        for (int c = 0; c < 8; ++c) O[c] += __shfl_xor(O[c], off, 64);
    }

    if (slot == 0) {
        const float inv = 1.f / S;
        uint4 urs = *(const uint4*)(resin + (size_t)d * C + base_c);
        float r[8];
        r[0] = bflo(urs.x); r[1] = bfhi(urs.x);
        r[2] = bflo(urs.y); r[3] = bfhi(urs.y);
        r[4] = bflo(urs.z); r[5] = bfhi(urs.z);
        r[6] = bflo(urs.w); r[7] = bfhi(urs.w);
        #pragma unroll
        for (int c = 0; c < 8; ++c) {
            r[c] += O[c] * inv;
            if (RELU) r[c] = fmaxf(r[c], 0.f);
        }
        if (OUT_BF16) {
            ushort tmp[8];
            #pragma unroll
            for (int c = 0; c < 8; ++c) tmp[c] = f2bf(r[c]);
            *((uint4*)((ushort*)outp + (size_t)d * C + base_c)) = *(uint4*)tmp;
        } else {
            float* op = (float*)outp + (size_t)d * C + base_c;
            *(float4*)op       = make_float4(r[0], r[1], r[2], r[3]);
            *(float4*)(op + 4) = make_float4(r[4], r[5], r[6], r[7]);
        }
    }
}

// ===========================================================================
extern "C" void kernel_launch(void* const* d_in, const int* in_sizes, int n_in,
                              void* d_out, int out_size, void* d_ws, size_t ws_size,
                              hipStream_t stream) {
    const int*   ei  = (const int*)d_in[0];
    const float* emb = (const float*)d_in[1];
    const float* L1[7];
    const float* L2[7];
    for (int i = 0; i < 7; ++i) L1[i] = (const float*)d_in[2 + i];
    for (int i = 0; i < 7; ++i) L2[i] = (const float*)d_in[9 + i];
    float* out = (float*)d_out;

    const size_t NC = (size_t)N_NODES * C;
    ushort* xl  = (ushort*)d_ws;
    ushort* xr  = xl + NC;
    ushort* h   = xr + NC;
    ushort* r2  = h + NC;
    ushort* wb  = r2 + NC;
    int* row_off = (int*)(wb + 6 * 16384);       // N+1 (+1 pad)
    int* cursor  = row_off + (N_NODES + 2);
    int* bsum    = cursor + N_NODES;
    int* cnt     = bsum + 512;
    int* colsrc  = cnt + N_NODES;

    // ---- CSR build (shared by both layers) ----
    hipMemsetAsync(cnt, 0, N_NODES * sizeof(int), stream);
    hist_kernel<<<(E_TOT + 255) / 256, 256, 0, stream>>>(ei, cnt);
    scan_block<<<NB_SCAN, 256, 0, stream>>>(cnt, row_off, bsum);
    scan_tops<<<1, 512, 0, stream>>>(bsum);
    add_off<<<NB_SCAN, 256, 0, stream>>>(row_off, bsum, cursor);
    scatter_kernel<<<(E_TOT + 255) / 256, 256, 0, stream>>>(ei, cursor, colsrc);

    conv_w<<<48, 256, 0, stream>>>(L1[0], L1[2], L1[5], L2[0], L2[2], L2[5], wb);

    const int gblocks = (N_NODES + 63) / 64;

    // ---- layer 1 ----
    gemm3_mfma<1><<<gblocks, 512, 0, stream>>>(emb, wb, L1[1], L1[3], L1[6], xl, xr, h);
    node_kernel<1, 1><<<N_NODES / 4, 256, 0, stream>>>(xl, xr, L1[4], row_off, colsrc, h, h);

    // ---- layer 2 ----
    gemm3_mfma<0><<<gblocks, 512, 0, stream>>>(h, wb + 3 * 16384, L2[1], L2[3], L2[6], xl, xr, r2);
    node_kernel<0, 0><<<N_NODES / 4, 256, 0, stream>>>(xl, xr, L2[4], row_off, colsrc, r2, out);
}